// Round 6
// baseline (711.001 us; speedup 1.0000x reference)
//
#include <hip/hip_runtime.h>
#include <hip/hip_cooperative_groups.h>

namespace cg = cooperative_groups;

#define NN 10000
#define NE 320000
#define ROW_WORDS 320   // 320*32 = 10240 bits >= 10000
#define MP 10112        // 158*64 padded rows
#define NBLK 512        // 2 blocks/CU x 256 CU — co-residency structurally guaranteed
#define NTHR 256
#define BN_EPS 1e-5f

typedef __attribute__((ext_vector_type(8))) short short8;
typedef __attribute__((ext_vector_type(4))) float f32x4;
typedef unsigned short u16;

struct Params {
    const float* x; const int* ei;
    const float* W0; const float* b0; const float* g0; const float* bb0;
    const float* W1; const float* b1; const float* g1; const float* bb1;
    const float* fW0; const float* fb0; const float* fW1; const float* fb1;
    float* out;
    unsigned int* bitmap; float* stats;   // stats: [0,512) conv0, [512,1024) conv1
    u16* H1;                              // aliases bitmap region (dead after degree)
    float* deg; u16* xs; u16* W0t; u16* W1t; u16* fW0t; u16* fW1t;
    u16* H2; u16* H3; float* cvec1; float* biasf0;
};

// ---------------- helpers ----------------
__device__ __forceinline__ void split1(float v, u16& h, u16& l) {
    unsigned int u = __float_as_uint(v);
    h = (u16)(u >> 16);
    float hf = __uint_as_float(u & 0xFFFF0000u);
    l = (u16)(__float_as_uint(v - hf) >> 16);
}

__device__ __forceinline__ void gll16(const void* g, void* l) {
    __builtin_amdgcn_global_load_lds(
        (const __attribute__((address_space(1))) unsigned int*)g,
        (__attribute__((address_space(3))) unsigned int*)l, 16, 0, 0);
}

// ---------------- splitW: Wt[n][k] = split(scale_k * W[k][n]) ----------------
__device__ void splitW_dev(const float* __restrict__ W, int K, int N, int Kp, int Np,
                           const float* __restrict__ stats, const float* __restrict__ g,
                           u16* __restrict__ Wt, int bx, int by, char* smem) {
    float (*tile)[65] = (float(*)[65])smem;   // 64x65 fp32 = 16.6 KB
    int t = threadIdx.x;
    int bk = bx * 64, bn = by * 64;
    const float invM = 1.f / (float)NN;
    #pragma unroll
    for (int p = 0; p < 4; ++p) {
        int kk = (t >> 4) + p * 16;
        int nc = (t & 15) * 4;
        int k = bk + kk;
        float4 v = {0.f, 0.f, 0.f, 0.f};
        if (k < K && bn + nc + 3 < N) {
            v = *(const float4*)&W[(size_t)k * N + bn + nc];
            float s = 1.f;
            if (stats) {
                float mean = stats[k] * invM;
                float var = stats[256 + k] * invM - mean * mean;
                s = g[k] * rsqrtf(var + BN_EPS);
            }
            v.x *= s; v.y *= s; v.z *= s; v.w *= s;
        }
        tile[kk][nc] = v.x; tile[kk][nc + 1] = v.y;
        tile[kk][nc + 2] = v.z; tile[kk][nc + 3] = v.w;
    }
    __syncthreads();
    int nn = t >> 2;
    int kk0 = (t & 3) * 16;
    u16 hs[16], ls[16];
    #pragma unroll
    for (int j = 0; j < 16; ++j) split1(tile[kk0 + j][nn], hs[j], ls[j]);
    size_t ob = (size_t)(bn + nn) * Kp + bk + kk0;
    size_t lo = (size_t)Np * Kp;
    *(short8*)&Wt[ob] = *(short8*)hs;
    *(short8*)&Wt[ob + 8] = *(short8*)&hs[8];
    *(short8*)&Wt[lo + ob] = *(short8*)ls;
    *(short8*)&Wt[lo + ob + 8] = *(short8*)&ls[8];
    __syncthreads();   // smem reused by callers
}

// ---------------- colvec: out[n] = base[n] + sum_k sh_k * W[k][n] ----------------
__device__ void colvec_dev(const float* __restrict__ W, int K, int N,
                           const float* __restrict__ stats, const float* __restrict__ g,
                           const float* __restrict__ bb, const float* __restrict__ base,
                           float* __restrict__ outv, int cb, char* smem) {
    float (*red)[64] = (float(*)[64])smem;
    int nl = threadIdx.x & 63;
    int n = cb * 64 + nl;
    int kq = threadIdx.x >> 6;
    const float invM = 1.f / (float)NN;
    float s = 0.f;
    for (int k = kq; k < K; k += 4) {
        float mean = stats[k] * invM;
        float var = stats[256 + k] * invM - mean * mean;
        float scl = g[k] * rsqrtf(var + BN_EPS);
        float sh = bb[k] - mean * scl;
        s += sh * W[(size_t)k * N + n];
    }
    red[kq][nl] = s;
    __syncthreads();
    if (kq == 0 && n < N)
        outv[n] = (base ? base[n] : 0.f) + red[0][nl] + red[1][nl] + red[2][nl] + red[3][nl];
    __syncthreads();
}

// ---------------- 64x64x64 split-bf16 MFMA GEMM tile ----------------
// degmode: 0 none; 1 pre = deg_r*acc + bias, store deg_r*relu (conv0, deg-free A);
//          2 pre = acc + bias + deg_r*cvec_n (conv1).
__device__ void gemm_tile(const u16* __restrict__ Ahi, const u16* __restrict__ Alo,
                          const u16* __restrict__ Bhi, const u16* __restrict__ Blo,
                          int Kp, int M, int N,
                          const float* __restrict__ bias, const float* __restrict__ cvec,
                          const float* __restrict__ deg, int degmode,
                          float* __restrict__ stats,
                          u16* __restrict__ Ohi, u16* __restrict__ Olo,
                          float* __restrict__ Ofp, int No,
                          int bx, int by, char* smem) {
    const int t = threadIdx.x;
    const int lane = t & 63;
    const int w = t >> 6;
    const int q = lane >> 4;
    const int l16 = lane & 15;
    const int m7 = l16 & 7;
    const int row0 = by * 64;
    const int col0 = bx * 64;

    const u16* bases[4] = {Ahi, Alo, Bhi, Blo};
    const u16* srcs[8];
    unsigned dstoff[8];
    #pragma unroll
    for (int i = 0; i < 8; ++i) {
        int gi = w + i * 4;
        int reg = i >> 1;
        int j = gi & 7;
        int rb = (reg < 2) ? row0 : col0;
        int r = j * 8 + (lane >> 3);
        int c = (lane & 7) ^ (r & 7);
        srcs[i] = bases[reg] + (size_t)(rb + r) * Kp + c * 8;
        dstoff[i] = reg * 8192 + j * 1024;
    }

    f32x4 acc[4];
    #pragma unroll
    for (int s = 0; s < 4; ++s) acc[s] = (f32x4){0.f, 0.f, 0.f, 0.f};

    #pragma unroll
    for (int i = 0; i < 8; ++i) { gll16(srcs[i], smem + dstoff[i]); srcs[i] += 64; }

    for (int k0 = 0; k0 < Kp; k0 += 64) {
        __syncthreads();                       // drain loads: tile resident
        short8 ah[2], al[2], bh[2][4], bl[2][4];
        #pragma unroll
        for (int kc = 0; kc < 2; ++kc) {
            int aoff = (w * 16 + l16) * 128 + (((kc * 4 + q) ^ m7) * 16);
            ah[kc] = *(const short8*)(smem + aoff);
            al[kc] = *(const short8*)(smem + 8192 + aoff);
            #pragma unroll
            for (int s = 0; s < 4; ++s) {
                int boff = (s * 16 + l16) * 128 + (((kc * 4 + q) ^ m7) * 16);
                bh[kc][s] = *(const short8*)(smem + 16384 + boff);
                bl[kc][s] = *(const short8*)(smem + 24576 + boff);
            }
        }
        __syncthreads();                       // all waves done reading LDS
        if (k0 + 64 < Kp) {                    // prefetch next tile; overlaps MFMA
            #pragma unroll
            for (int i = 0; i < 8; ++i) { gll16(srcs[i], smem + dstoff[i]); srcs[i] += 64; }
        }
        #pragma unroll
        for (int kc = 0; kc < 2; ++kc)
            #pragma unroll
            for (int s = 0; s < 4; ++s) {
                acc[s] = __builtin_amdgcn_mfma_f32_16x16x32_bf16(al[kc], bh[kc][s], acc[s], 0, 0, 0);
                acc[s] = __builtin_amdgcn_mfma_f32_16x16x32_bf16(ah[kc], bl[kc][s], acc[s], 0, 0, 0);
                acc[s] = __builtin_amdgcn_mfma_f32_16x16x32_bf16(ah[kc], bh[kc][s], acc[s], 0, 0, 0);
            }
    }

    // ---- epilogue ----
    int growb = row0 + w * 16 + q * 4;
    float dgv[4];
    #pragma unroll
    for (int r = 0; r < 4; ++r)
        dgv[r] = degmode ? ((growb + r < M) ? deg[growb + r] : 0.f) : 1.f;
    #pragma unroll
    for (int s = 0; s < 4; ++s) {
        int gc = col0 + s * 16 + l16;
        float bia = (gc < N) ? bias[gc] : 0.f;
        float cv = (cvec && gc < N) ? cvec[gc] : 0.f;
        float s_sum = 0.f, ss_sum = 0.f;
        #pragma unroll
        for (int r = 0; r < 4; ++r) {
            int grow = growb + r;
            bool real = (grow < M) && (gc < N);
            float pre;
            if (degmode == 1) pre = fmaf(dgv[r], acc[s][r], bia);
            else {
                pre = acc[s][r] + bia;
                if (degmode == 2) pre = fmaf(dgv[r], cv, pre);
            }
            float v = fmaxf(pre, 0.f);
            if (!real) v = 0.f;
            s_sum += v; ss_sum += v * v;
            if (Ofp) {
                if (real) Ofp[(size_t)grow * No + gc] = v;
            } else {
                float vo = (degmode == 1) ? v * dgv[r] : v;
                u16 h, l; split1(vo, h, l);
                Ohi[(size_t)grow * No + gc] = h;
                Olo[(size_t)grow * No + gc] = l;
            }
        }
        if (stats) {
            s_sum  += __shfl_xor(s_sum, 16);  s_sum  += __shfl_xor(s_sum, 32);
            ss_sum += __shfl_xor(ss_sum, 16); ss_sum += __shfl_xor(ss_sum, 32);
            if (lane < 16 && gc < N) {
                atomicAdd(&stats[gc], s_sum);
                atomicAdd(&stats[256 + gc], ss_sum);
            }
        }
    }
}

// ---------------- x split (deg-free): xs[r][512] hi|lo, rows of 16 per group ----
__device__ void xsplit_dev(const float* __restrict__ x, u16* __restrict__ xs, int gblk) {
    int t = threadIdx.x;
    int r0 = gblk * 16 + (t >> 4);
    int l = t & 15;
    u16* xlo = xs + (size_t)MP * 512;
    #pragma unroll
    for (int j = 0; j < 8; ++j) {
        int k = (l + j * 16) * 4;
        float vals[4] = {0.f, 0.f, 0.f, 0.f};
        if (r0 < NN && k < 500) {
            float4 v = *(const float4*)&x[(size_t)r0 * 500 + k];
            vals[0] = v.x; vals[1] = v.y; vals[2] = v.z; vals[3] = v.w;
        }
        ushort4 hs, ls;
        split1(vals[0], hs.x, ls.x); split1(vals[1], hs.y, ls.y);
        split1(vals[2], hs.z, ls.z); split1(vals[3], hs.w, ls.w);
        *(ushort4*)&xs[(size_t)r0 * 512 + k] = hs;
        *(ushort4*)&xlo[(size_t)r0 * 512 + k] = ls;
    }
}

__device__ void degree_dev(const unsigned int* __restrict__ bitmap, float* __restrict__ deg,
                           int gblk) {
    int t = threadIdx.x;
    int r = gblk * 16 + (t >> 4), l = t & 15;
    int cnt = 0;
    if (r < NN)
        for (int wd = l; wd < ROW_WORDS; wd += 16)
            cnt += __popc(bitmap[(size_t)r * ROW_WORDS + wd]);
    cnt += __shfl_down(cnt, 8, 16);
    cnt += __shfl_down(cnt, 4, 16);
    cnt += __shfl_down(cnt, 2, 16);
    cnt += __shfl_down(cnt, 1, 16);
    if (l == 0 && r < NN) deg[r] = (float)cnt;
}

// ---------------- cooperative mega kernel (grid-stride phases) ----------------
__global__ __launch_bounds__(256, 2) void gcn_mega(Params p) {
    __shared__ char smem[32768];
    cg::grid_group grid = cg::this_grid();
    const int b = blockIdx.x;
    const int t = threadIdx.x;
    const int gtid = b * NTHR + t;

    // P0: zero bitmap+stats; split x, W0, fW1
    {
        uint4 z4 = {0u, 0u, 0u, 0u};
        uint4* z = (uint4*)p.bitmap;          // bitmap 12.8MB + stats 4KB contiguous
        for (int i = gtid; i < 800256; i += NBLK * NTHR) z[i] = z4;
        for (int g = b; g < 632; g += NBLK) xsplit_dev(p.x, p.xs, g);
        if (b < 32)
            splitW_dev(p.W0, 500, 256, 512, 256, nullptr, nullptr, p.W0t, b & 7, b >> 3, smem);
        else if (b < 34)
            splitW_dev(p.fW1, 128, 40, 128, 64, nullptr, nullptr, p.fW1t, b - 32, 0, smem);
    }
    grid.sync();
    // P1: scatter edges into dedup bitmap
    for (int e = gtid; e < NE + NN; e += NBLK * NTHR) {
        if (e < NE) {
            int i = p.ei[e], j = p.ei[NE + e];
            atomicOr(&p.bitmap[i * ROW_WORDS + (j >> 5)], 1u << (j & 31));
        } else {
            int i = e - NE;
            atomicOr(&p.bitmap[i * ROW_WORDS + (i >> 5)], 1u << (i & 31));
        }
    }
    grid.sync();
    // P2: degree
    for (int g = b; g < 632; g += NBLK) degree_dev(p.bitmap, p.deg, g);
    grid.sync();
    // P3: conv0  H1 = deg ⊙ relu(deg⊙(x@W0) + b0); stats0
    for (int tile = b; tile < 632; tile += NBLK)
        gemm_tile(p.xs, p.xs + (size_t)MP * 512, p.W0t, p.W0t + 256 * 512, 512, NN, 256,
                  p.b0, nullptr, p.deg, 1, p.stats, p.H1, p.H1 + (size_t)MP * 256, nullptr, 256,
                  tile & 3, tile >> 2, smem);
    grid.sync();
    // P4: fold BN0 into W1 + cvec1
    if (b < 16)
        splitW_dev(p.W1, 256, 256, 256, 256, p.stats, p.g0, p.W1t, b & 3, b >> 2, smem);
    else if (b < 20)
        colvec_dev(p.W1, 256, 256, p.stats, p.g0, p.bb0, nullptr, p.cvec1, b - 16, smem);
    grid.sync();
    // P5: conv1  H2 = relu(H1@(sc0⊙W1) + deg*cvec1 + b1); stats1
    for (int tile = b; tile < 632; tile += NBLK)
        gemm_tile(p.H1, p.H1 + (size_t)MP * 256, p.W1t, p.W1t + 256 * 256, 256, NN, 256,
                  p.b1, p.cvec1, p.deg, 2, p.stats + 512, p.H2, p.H2 + (size_t)MP * 256, nullptr, 256,
                  tile & 3, tile >> 2, smem);
    grid.sync();
    // P6: fold BN1 into fW0 + biasf0
    if (b < 8)
        splitW_dev(p.fW0, 256, 128, 256, 128, p.stats + 512, p.g1, p.fW0t, b & 3, b >> 2, smem);
    else if (b < 10)
        colvec_dev(p.fW0, 256, 128, p.stats + 512, p.g1, p.bb1, p.fb0, p.biasf0, b - 8, smem);
    grid.sync();
    // P7: fc0  H3 = relu(H2@(sc1⊙fW0) + biasf0)
    if (b < 316)
        gemm_tile(p.H2, p.H2 + (size_t)MP * 256, p.fW0t, p.fW0t + 128 * 256, 256, NN, 128,
                  p.biasf0, nullptr, nullptr, 0, nullptr, p.H3, p.H3 + (size_t)MP * 128, nullptr, 128,
                  b & 1, b >> 1, smem);
    grid.sync();
    // P8: fc1  out = relu(H3@fW1 + fb1), fp32
    if (b < 158)
        gemm_tile(p.H3, p.H3 + (size_t)MP * 128, p.fW1t, p.fW1t + 64 * 128, 128, NN, 40,
                  p.fb1, nullptr, nullptr, 0, nullptr, nullptr, nullptr, p.out, 40,
                  0, b, smem);
}

// ---------------- fallback multi-kernel path (round-4 proven) ----------------
__global__ void scatter_bits(const int* __restrict__ ei, unsigned int* __restrict__ bitmap) {
    int t = blockIdx.x * blockDim.x + threadIdx.x;
    if (t < NE) {
        int i = ei[t];
        int j = ei[NE + t];
        atomicOr(&bitmap[i * ROW_WORDS + (j >> 5)], 1u << (j & 31));
    } else if (t < NE + NN) {
        int i = t - NE;
        atomicOr(&bitmap[i * ROW_WORDS + (i >> 5)], 1u << (i & 31));
    }
}

__global__ __launch_bounds__(256) void prep_fb(Params p) {
    __shared__ char smem[32768];
    int b = blockIdx.x;
    if (b < 632) {
        degree_dev(p.bitmap, p.deg, b);
        xsplit_dev(p.x, p.xs, b);
    } else if (b < 664) {
        int idx = b - 632;
        splitW_dev(p.W0, 500, 256, 512, 256, nullptr, nullptr, p.W0t, idx & 7, idx >> 3, smem);
    } else {
        splitW_dev(p.fW1, 128, 40, 128, 64, nullptr, nullptr, p.fW1t, b - 664, 0, smem);
    }
}

__global__ __launch_bounds__(256) void post_fb(const float* W, int K, int N, int Kp, int Np,
                                               const float* stats, const float* g,
                                               const float* bb, u16* Wt,
                                               int ntiles, int tx, const float* cvbase,
                                               float* cvout) {
    __shared__ char smem[32768];
    int b = blockIdx.x;
    if (b < ntiles)
        splitW_dev(W, K, N, Kp, Np, stats, g, Wt, b % tx, b / tx, smem);
    else
        colvec_dev(W, K, N, stats, g, bb, cvbase, cvout, b - ntiles, smem);
}

__global__ __launch_bounds__(256, 3) void gemm_fb(const u16* Ahi, const u16* Alo,
                                                  const u16* Bhi, const u16* Blo,
                                                  int Kp, int M, int N,
                                                  const float* bias, const float* cvec,
                                                  const float* deg, int degmode,
                                                  float* stats, u16* Ohi, u16* Olo,
                                                  float* Ofp, int No) {
    __shared__ char smem[32768];
    gemm_tile(Ahi, Alo, Bhi, Blo, Kp, M, N, bias, cvec, deg, degmode, stats,
              Ohi, Olo, Ofp, No, blockIdx.x, blockIdx.y, smem);
}

// ---------------- launch ----------------

extern "C" void kernel_launch(void* const* d_in, const int* in_sizes, int n_in,
                              void* d_out, int out_size, void* d_ws, size_t ws_size,
                              hipStream_t stream) {
    Params p;
    p.x   = (const float*)d_in[0];
    p.ei  = (const int*)d_in[1];
    p.W0  = (const float*)d_in[2];
    p.b0  = (const float*)d_in[3];
    p.g0  = (const float*)d_in[4];
    p.bb0 = (const float*)d_in[5];
    p.W1  = (const float*)d_in[6];
    p.b1  = (const float*)d_in[7];
    p.g1  = (const float*)d_in[8];
    p.bb1 = (const float*)d_in[9];
    p.fW0 = (const float*)d_in[10];
    p.fb0 = (const float*)d_in[11];
    p.fW1 = (const float*)d_in[12];
    p.fb1 = (const float*)d_in[13];
    p.out = (float*)d_out;

    char* ws = (char*)d_ws;
    auto carve = [&](size_t bytes) { char* q = ws; ws += (bytes + 255) & ~(size_t)255; return q; };

    const size_t BITMAP_BYTES = (size_t)NN * ROW_WORDS * 4;   // 12,800,000
    char* region0 = carve(BITMAP_BYTES + 4096);
    p.bitmap = (unsigned int*)region0;
    p.stats  = (float*)(region0 + BITMAP_BYTES);
    p.H1     = (u16*)region0;                                 // reuse after degree pass

    p.deg    = (float*)carve(MP * 4);
    p.xs     = (u16*)carve((size_t)2 * MP * 512 * 2);
    p.W0t    = (u16*)carve((size_t)2 * 256 * 512 * 2);
    p.W1t    = (u16*)carve((size_t)2 * 256 * 256 * 2);
    p.fW0t   = (u16*)carve((size_t)2 * 128 * 256 * 2);
    p.fW1t   = (u16*)carve((size_t)2 * 64 * 128 * 2);
    p.H2     = (u16*)carve((size_t)2 * MP * 256 * 2);
    p.H3     = (u16*)carve((size_t)2 * MP * 128 * 2);
    p.cvec1  = (float*)carve(256 * 4);
    p.biasf0 = (float*)carve(128 * 4);

    void* kargs[] = {(void*)&p};
    hipError_t err = hipLaunchCooperativeKernel((const void*)gcn_mega, dim3(NBLK), dim3(NTHR),
                                                kargs, 0, stream);
    if (err == hipSuccess) return;

    // ---- fallback: proven multi-kernel sequence ----
    (void)hipGetLastError();   // clear error state
    dim3 blk(256);
    hipMemsetAsync(region0, 0, BITMAP_BYTES + 4096, stream);
    scatter_bits<<<(NE + NN + 255) / 256, blk, 0, stream>>>(p.ei, p.bitmap);
    prep_fb<<<666, blk, 0, stream>>>(p);
    gemm_fb<<<dim3(4, 158), blk, 0, stream>>>(
        p.xs, p.xs + (size_t)MP * 512, p.W0t, p.W0t + 256 * 512, 512, NN, 256,
        p.b0, nullptr, p.deg, 1, p.stats, p.H1, p.H1 + (size_t)MP * 256, nullptr, 256);
    post_fb<<<20, blk, 0, stream>>>(p.W1, 256, 256, 256, 256, p.stats, p.g0, p.bb0, p.W1t,
                                    16, 4, nullptr, p.cvec1);
    gemm_fb<<<dim3(4, 158), blk, 0, stream>>>(
        p.H1, p.H1 + (size_t)MP * 256, p.W1t, p.W1t + 256 * 256, 256, NN, 256,
        p.b1, p.cvec1, p.deg, 2, p.stats + 512, p.H2, p.H2 + (size_t)MP * 256, nullptr, 256);
    post_fb<<<10, blk, 0, stream>>>(p.fW0, 256, 128, 256, 128, p.stats + 512, p.g1, p.bb1,
                                    p.fW0t, 8, 4, p.fb0, p.biasf0);
    gemm_fb<<<dim3(2, 158), blk, 0, stream>>>(
        p.H2, p.H2 + (size_t)MP * 256, p.fW0t, p.fW0t + 128 * 256, 256, NN, 128,
        p.biasf0, nullptr, nullptr, 0, nullptr, p.H3, p.H3 + (size_t)MP * 128, nullptr, 128);
    gemm_fb<<<dim3(1, 158), blk, 0, stream>>>(
        p.H3, p.H3 + (size_t)MP * 128, p.fW1t, p.fW1t + 64 * 128, 128, NN, 40,
        p.fb1, nullptr, nullptr, 0, nullptr, nullptr, nullptr, p.out, 40);
}

// Round 7
// 235.185 us; speedup vs baseline: 3.0232x; 3.0232x over previous
//
#include <hip/hip_runtime.h>

#define NN 10000
#define NE 320000
#define ROW_WORDS 320   // 320*32 = 10240 bits >= 10000
#define MP 10112        // 158*64 padded rows
#define BN_EPS 1e-5f

typedef __attribute__((ext_vector_type(8))) short short8;
typedef __attribute__((ext_vector_type(4))) float f32x4;
typedef unsigned short u16;

// ---------------- helpers ----------------
__device__ __forceinline__ void split1(float v, u16& h, u16& l) {
    unsigned int u = __float_as_uint(v);
    h = (u16)(u >> 16);
    float hf = __uint_as_float(u & 0xFFFF0000u);
    l = (u16)(__float_as_uint(v - hf) >> 16);
}

__device__ __forceinline__ void gll16(const void* g, void* l) {
    __builtin_amdgcn_global_load_lds(
        (const __attribute__((address_space(1))) unsigned int*)g,
        (__attribute__((address_space(3))) unsigned int*)l, 16, 0, 0);
}

// ---------------- scatter: dedup bitmap ----------------
__global__ void scatter_bits(const int* __restrict__ ei, unsigned int* __restrict__ bitmap) {
    int t = blockIdx.x * blockDim.x + threadIdx.x;
    if (t < NE) {
        int i = ei[t];
        int j = ei[NE + t];
        atomicOr(&bitmap[i * ROW_WORDS + (j >> 5)], 1u << (j & 31));
    } else if (t < NE + NN) {
        int i = t - NE;
        atomicOr(&bitmap[i * ROW_WORDS + (i >> 5)], 1u << (i & 31));
    }
}

// ---------------- prep device fns (proven round 4/6) ----------------
__device__ void splitW_dev(const float* __restrict__ W, int K, int N, int Kp, int Np,
                           u16* __restrict__ Wt, int bx, int by, char* smem) {
    float (*tile)[65] = (float(*)[65])smem;
    int t = threadIdx.x;
    int bk = bx * 64, bn = by * 64;
    #pragma unroll
    for (int p = 0; p < 4; ++p) {
        int kk = (t >> 4) + p * 16;
        int nc = (t & 15) * 4;
        int k = bk + kk;
        float4 v = {0.f, 0.f, 0.f, 0.f};
        if (k < K && bn + nc + 3 < N)
            v = *(const float4*)&W[(size_t)k * N + bn + nc];
        tile[kk][nc] = v.x; tile[kk][nc + 1] = v.y;
        tile[kk][nc + 2] = v.z; tile[kk][nc + 3] = v.w;
    }
    __syncthreads();
    int nn = t >> 2;
    int kk0 = (t & 3) * 16;
    u16 hs[16], ls[16];
    #pragma unroll
    for (int j = 0; j < 16; ++j) split1(tile[kk0 + j][nn], hs[j], ls[j]);
    size_t ob = (size_t)(bn + nn) * Kp + bk + kk0;
    size_t lo = (size_t)Np * Kp;
    *(short8*)&Wt[ob] = *(short8*)hs;
    *(short8*)&Wt[ob + 8] = *(short8*)&hs[8];
    *(short8*)&Wt[lo + ob] = *(short8*)ls;
    *(short8*)&Wt[lo + ob + 8] = *(short8*)&ls[8];
}

__device__ void xsplit_dev(const float* __restrict__ x, u16* __restrict__ xs, int gblk) {
    int t = threadIdx.x;
    int r0 = gblk * 16 + (t >> 4);
    int l = t & 15;
    u16* xlo = xs + (size_t)MP * 512;
    #pragma unroll
    for (int j = 0; j < 8; ++j) {
        int k = (l + j * 16) * 4;
        float vals[4] = {0.f, 0.f, 0.f, 0.f};
        if (r0 < NN && k < 500) {
            float4 v = *(const float4*)&x[(size_t)r0 * 500 + k];
            vals[0] = v.x; vals[1] = v.y; vals[2] = v.z; vals[3] = v.w;
        }
        ushort4 hs, ls;
        split1(vals[0], hs.x, ls.x); split1(vals[1], hs.y, ls.y);
        split1(vals[2], hs.z, ls.z); split1(vals[3], hs.w, ls.w);
        *(ushort4*)&xs[(size_t)r0 * 512 + k] = hs;
        *(ushort4*)&xlo[(size_t)r0 * 512 + k] = ls;
    }
}

__device__ void degree_dev(const unsigned int* __restrict__ bitmap, float* __restrict__ deg,
                           int gblk) {
    int t = threadIdx.x;
    int r = gblk * 16 + (t >> 4), l = t & 15;
    int cnt = 0;
    if (r < NN)
        for (int wd = l; wd < ROW_WORDS; wd += 16)
            cnt += __popc(bitmap[(size_t)r * ROW_WORDS + wd]);
    cnt += __shfl_down(cnt, 8, 16);
    cnt += __shfl_down(cnt, 4, 16);
    cnt += __shfl_down(cnt, 2, 16);
    cnt += __shfl_down(cnt, 1, 16);
    if (l == 0 && r < NN) deg[r] = (float)cnt;
}

// ---------------- prep: degree + split x + split W0 + split fW1 ----------------
__global__ __launch_bounds__(256)
void prep(const unsigned int* __restrict__ bitmap, const float* __restrict__ x,
          const float* __restrict__ W0, const float* __restrict__ fW1,
          float* __restrict__ deg, u16* __restrict__ xs,
          u16* __restrict__ W0t, u16* __restrict__ fW1t) {
    __shared__ char smem[16704];
    int b = blockIdx.x;
    if (b < 632) {
        degree_dev(bitmap, deg, b);
        xsplit_dev(x, xs, b);
    } else if (b < 664) {
        int idx = b - 632;
        splitW_dev(W0, 500, 256, 512, 256, W0t, idx & 7, idx >> 3, smem);
    } else {
        splitW_dev(fW1, 128, 40, 128, 64, fW1t, b - 664, 0, smem);
    }
}

// ---------------- conv0 GEMM (proven): A,B pre-split, gll16 staging ----------------
// H1 = deg ⊙ relu(deg*(x@W0) + b0); stats over relu output
__global__ __launch_bounds__(256, 3)
void conv0_gemm(const u16* __restrict__ Ahi, const u16* __restrict__ Alo,
                const u16* __restrict__ Bhi, const u16* __restrict__ Blo,
                const float* __restrict__ bias, const float* __restrict__ deg,
                float* __restrict__ stats, u16* __restrict__ Ohi, u16* __restrict__ Olo) {
    __shared__ char smem[32768];   // Ahi|Alo|Bhi|Blo, 8 KB each
    const int Kp = 512, M = NN, No = 256;
    const int t = threadIdx.x;
    const int lane = t & 63;
    const int w = t >> 6;
    const int q = lane >> 4;
    const int l16 = lane & 15;
    const int m7 = l16 & 7;
    const int row0 = blockIdx.y * 64;
    const int col0 = blockIdx.x * 64;

    const u16* bases[4] = {Ahi, Alo, Bhi, Blo};
    const u16* srcs[8];
    unsigned dstoff[8];
    #pragma unroll
    for (int i = 0; i < 8; ++i) {
        int gi = w + i * 4;
        int reg = i >> 1;
        int j = gi & 7;
        int rb = (reg < 2) ? row0 : col0;
        int r = j * 8 + (lane >> 3);
        int c = (lane & 7) ^ (r & 7);
        srcs[i] = bases[reg] + (size_t)(rb + r) * Kp + c * 8;
        dstoff[i] = reg * 8192 + j * 1024;
    }

    f32x4 acc[4];
    #pragma unroll
    for (int s = 0; s < 4; ++s) acc[s] = (f32x4){0.f, 0.f, 0.f, 0.f};

    #pragma unroll
    for (int i = 0; i < 8; ++i) { gll16(srcs[i], smem + dstoff[i]); srcs[i] += 64; }

    for (int k0 = 0; k0 < Kp; k0 += 64) {
        __syncthreads();
        short8 ah[2], al[2], bh[2][4], bl[2][4];
        #pragma unroll
        for (int kc = 0; kc < 2; ++kc) {
            int aoff = (w * 16 + l16) * 128 + (((kc * 4 + q) ^ m7) * 16);
            ah[kc] = *(const short8*)(smem + aoff);
            al[kc] = *(const short8*)(smem + 8192 + aoff);
            #pragma unroll
            for (int s = 0; s < 4; ++s) {
                int boff = (s * 16 + l16) * 128 + (((kc * 4 + q) ^ m7) * 16);
                bh[kc][s] = *(const short8*)(smem + 16384 + boff);
                bl[kc][s] = *(const short8*)(smem + 24576 + boff);
            }
        }
        __syncthreads();
        if (k0 + 64 < Kp) {
            #pragma unroll
            for (int i = 0; i < 8; ++i) { gll16(srcs[i], smem + dstoff[i]); srcs[i] += 64; }
        }
        #pragma unroll
        for (int kc = 0; kc < 2; ++kc)
            #pragma unroll
            for (int s = 0; s < 4; ++s) {
                acc[s] = __builtin_amdgcn_mfma_f32_16x16x32_bf16(al[kc], bh[kc][s], acc[s], 0, 0, 0);
                acc[s] = __builtin_amdgcn_mfma_f32_16x16x32_bf16(ah[kc], bl[kc][s], acc[s], 0, 0, 0);
                acc[s] = __builtin_amdgcn_mfma_f32_16x16x32_bf16(ah[kc], bh[kc][s], acc[s], 0, 0, 0);
            }
    }

    int growb = row0 + w * 16 + q * 4;
    float dgv[4];
    #pragma unroll
    for (int r = 0; r < 4; ++r) dgv[r] = (growb + r < M) ? deg[growb + r] : 0.f;
    #pragma unroll
    for (int s = 0; s < 4; ++s) {
        int gc = col0 + s * 16 + l16;
        float bia = bias[gc];
        float s_sum = 0.f, ss_sum = 0.f;
        #pragma unroll
        for (int r = 0; r < 4; ++r) {
            int grow = growb + r;
            bool real = grow < M;
            float v = fmaxf(fmaf(dgv[r], acc[s][r], bia), 0.f);
            if (!real) v = 0.f;
            s_sum += v; ss_sum += v * v;
            float vo = v * dgv[r];
            u16 h, l; split1(vo, h, l);
            Ohi[(size_t)grow * No + gc] = h;
            Olo[(size_t)grow * No + gc] = l;
        }
        s_sum  += __shfl_xor(s_sum, 16);  s_sum  += __shfl_xor(s_sum, 32);
        ss_sum += __shfl_xor(ss_sum, 16); ss_sum += __shfl_xor(ss_sum, 32);
        if (lane < 16) {
            atomicAdd(&stats[gc], s_sum);
            atomicAdd(&stats[256 + gc], ss_sum);
        }
    }
}

// ---------------- conv1 with in-kernel BN0 fold of W1 ----------------
// H2 = relu(H1@(sc0⊙W1) + deg*cvec + b1); stats1 over relu output
__global__ __launch_bounds__(256, 2)
void conv1_fold(const u16* __restrict__ Ahi, const u16* __restrict__ Alo,
                const float* __restrict__ W1, const float* __restrict__ stats0,
                const float* __restrict__ g0, const float* __restrict__ bb0,
                const float* __restrict__ b1, const float* __restrict__ deg,
                float* __restrict__ stats1, u16* __restrict__ Ohi, u16* __restrict__ Olo) {
    __shared__ char smem[32768];   // Ahi|Alo|Bhi|Blo, 8 KB each
    __shared__ float scl[256], sh[256], cred[256], cvec[64];
    const int Kp = 256, M = NN, No = 256;
    const int t = threadIdx.x;
    const int lane = t & 63;
    const int w = t >> 6;
    const int q = lane >> 4;
    const int l16 = lane & 15;
    const int m7 = l16 & 7;
    const int row0 = blockIdx.y * 64;
    const int col0 = blockIdx.x * 64;

    // A staging: 16 wave-loads (hi 8 + lo 8), 4 per wave
    const u16* srcs[4];
    unsigned dstoff[4];
    #pragma unroll
    for (int i = 0; i < 4; ++i) {
        int gi = w + i * 4;
        int plane = gi >> 3, j = gi & 7;
        int r = j * 8 + (lane >> 3);
        int c = (lane & 7) ^ (r & 7);
        srcs[i] = (plane ? Alo : Ahi) + (size_t)(row0 + r) * Kp + c * 8;
        dstoff[i] = plane * 8192 + j * 1024;
    }
    #pragma unroll
    for (int i = 0; i < 4; ++i) { gll16(srcs[i], smem + dstoff[i]); srcs[i] += 64; }

    // BN0 coefficients
    {
        float mean = stats0[t] * (1.f / NN);
        float var = stats0[256 + t] * (1.f / NN) - mean * mean;
        float s = g0[t] * rsqrtf(var + BN_EPS);
        scl[t] = s;
        sh[t] = bb0[t] - mean * s;
    }
    __syncthreads();
    // cvec[n] = sum_k sh[k]*W1[k][col0+n] for this block's 64-col strip
    {
        float s = 0.f;
        int n = col0 + (t & 63);
        for (int k = (t >> 6); k < 256; k += 4)
            s += sh[k] * W1[(size_t)k * 256 + n];
        cred[t] = s;
        __syncthreads();
        if (t < 64) cvec[t] = cred[t] + cred[t + 64] + cred[t + 128] + cred[t + 192];
    }
    // pre-load fold regs for B tile 0
    const int bn = t & 63;
    const int kb = (t >> 6) * 16;
    const int ch0 = (t >> 6) * 2;
    float vals[16];
    {
        const float* wp = W1 + (size_t)kb * 256 + col0 + bn;
        #pragma unroll
        for (int i = 0; i < 16; ++i) vals[i] = wp[(size_t)i * 256] * scl[kb + i];
    }

    f32x4 acc[4];
    #pragma unroll
    for (int s = 0; s < 4; ++s) acc[s] = (f32x4){0.f, 0.f, 0.f, 0.f};

    for (int k0 = 0; k0 < Kp; k0 += 64) {
        // write folded B tile to LDS (regs were loaded after previous barrier-2)
        {
            u16 hs[16], ls[16];
            #pragma unroll
            for (int i = 0; i < 16; ++i) split1(vals[i], hs[i], ls[i]);
            unsigned o0 = bn * 128 + ((ch0 ^ (bn & 7)) * 16);
            unsigned o1 = bn * 128 + (((ch0 + 1) ^ (bn & 7)) * 16);
            *(short8*)(smem + 16384 + o0) = *(short8*)&hs[0];
            *(short8*)(smem + 16384 + o1) = *(short8*)&hs[8];
            *(short8*)(smem + 24576 + o0) = *(short8*)&ls[0];
            *(short8*)(smem + 24576 + o1) = *(short8*)&ls[8];
        }
        __syncthreads();   // (1) gll A(k0) drained + B(k0) visible
        short8 ah[2], al[2], bh[2][4], bl[2][4];
        #pragma unroll
        for (int kc = 0; kc < 2; ++kc) {
            int aoff = (w * 16 + l16) * 128 + (((kc * 4 + q) ^ m7) * 16);
            ah[kc] = *(const short8*)(smem + aoff);
            al[kc] = *(const short8*)(smem + 8192 + aoff);
            #pragma unroll
            for (int s = 0; s < 4; ++s) {
                int boff = (s * 16 + l16) * 128 + (((kc * 4 + q) ^ m7) * 16);
                bh[kc][s] = *(const short8*)(smem + 16384 + boff);
                bl[kc][s] = *(const short8*)(smem + 24576 + boff);
            }
        }
        __syncthreads();   // (2) all reads done
        if (k0 + 64 < Kp) {
            #pragma unroll
            for (int i = 0; i < 4; ++i) { gll16(srcs[i], smem + dstoff[i]); srcs[i] += 64; }
            const float* wp = W1 + (size_t)(k0 + 64 + kb) * 256 + col0 + bn;
            #pragma unroll
            for (int i = 0; i < 16; ++i) vals[i] = wp[(size_t)i * 256] * scl[k0 + 64 + kb + i];
        }
        #pragma unroll
        for (int kc = 0; kc < 2; ++kc)
            #pragma unroll
            for (int s = 0; s < 4; ++s) {
                acc[s] = __builtin_amdgcn_mfma_f32_16x16x32_bf16(al[kc], bh[kc][s], acc[s], 0, 0, 0);
                acc[s] = __builtin_amdgcn_mfma_f32_16x16x32_bf16(ah[kc], bl[kc][s], acc[s], 0, 0, 0);
                acc[s] = __builtin_amdgcn_mfma_f32_16x16x32_bf16(ah[kc], bh[kc][s], acc[s], 0, 0, 0);
            }
    }

    int growb = row0 + w * 16 + q * 4;
    float dgv[4];
    #pragma unroll
    for (int r = 0; r < 4; ++r) dgv[r] = (growb + r < M) ? deg[growb + r] : 0.f;
    #pragma unroll
    for (int s = 0; s < 4; ++s) {
        int gc = col0 + s * 16 + l16;
        float bia = b1[gc];
        float cv = cvec[s * 16 + l16];
        float s_sum = 0.f, ss_sum = 0.f;
        #pragma unroll
        for (int r = 0; r < 4; ++r) {
            int grow = growb + r;
            bool real = grow < M;
            float v = fmaxf(fmaf(dgv[r], cv, acc[s][r] + bia), 0.f);
            if (!real) v = 0.f;
            s_sum += v; ss_sum += v * v;
            u16 h, l; split1(v, h, l);
            Ohi[(size_t)grow * No + gc] = h;
            Olo[(size_t)grow * No + gc] = l;
        }
        s_sum  += __shfl_xor(s_sum, 16);  s_sum  += __shfl_xor(s_sum, 32);
        ss_sum += __shfl_xor(ss_sum, 16); ss_sum += __shfl_xor(ss_sum, 32);
        if (lane < 16) {
            atomicAdd(&stats1[gc], s_sum);
            atomicAdd(&stats1[256 + gc], ss_sum);
        }
    }
}

// ---------------- fused fc0+fc1 with in-kernel BN1 fold of fW0 ----------------
// H3 = relu(BN1(H2)@fW0 + fb0) kept in LDS; out = relu(H3@fW1 + fb1)
__global__ __launch_bounds__(256, 1)
void fc_fused(const u16* __restrict__ H2hi, const u16* __restrict__ H2lo,
              const float* __restrict__ fW0, const float* __restrict__ stats1,
              const float* __restrict__ g1, const float* __restrict__ bb1,
              const float* __restrict__ fb0, const u16* __restrict__ fW1t,
              const float* __restrict__ fb1, float* __restrict__ out) {
    __shared__ char As[8192];           // A hi 4K | lo 4K (64 rows x 32 k)
    __shared__ u16 Bh[128 * 32], Bl[128 * 32];
    __shared__ u16 H3h[64 * 128], H3l[64 * 128];
    __shared__ float scl[256], sh[256], red[256], biasf[128];

    const int t = threadIdx.x;
    const int lane = t & 63;
    const int w = t >> 6;
    const int q = lane >> 4;
    const int l16 = lane & 15;
    const int row0 = blockIdx.x * 64;

    // A staging: 8 wave-loads (hi 4 + lo 4), 2 per wave; 16 rows x 32 k per load
    const u16* srcs[2];
    unsigned dstoff[2];
    #pragma unroll
    for (int i = 0; i < 2; ++i) {
        int gi = w + i * 4;
        int plane = gi >> 2, j = gi & 3;
        int r = j * 16 + (lane >> 2);
        int c = (lane & 3) ^ (r & 3);
        srcs[i] = (plane ? H2lo : H2hi) + (size_t)(row0 + r) * 256 + c * 8;
        dstoff[i] = plane * 4096 + j * 1024;
    }
    #pragma unroll
    for (int i = 0; i < 2; ++i) { gll16(srcs[i], As + dstoff[i]); srcs[i] += 32; }

    // BN1 coefficients
    {
        float mean = stats1[t] * (1.f / NN);
        float var = stats1[256 + t] * (1.f / NN) - mean * mean;
        float s = g1[t] * rsqrtf(var + BN_EPS);
        scl[t] = s;
        sh[t] = bb1[t] - mean * s;
    }
    __syncthreads();
    // biasf[n] = fb0[n] + sum_k sh[k]*fW0[k][n]
    {
        int n = t & 127;
        float s2 = 0.f;
        for (int k = (t >> 7); k < 256; k += 2)
            s2 += sh[k] * fW0[(size_t)k * 128 + n];
        red[t] = s2;
        __syncthreads();
        if (t < 128) biasf[t] = fb0[t] + red[t] + red[t + 128];
    }
    // pre-load fold regs for B tile 0 (BK=32)
    const int bn = t & 127;
    const int kb = (t >> 7) * 16;
    const int ch0 = (t >> 7) * 2;
    float vals[16];
    {
        const float* wp = fW0 + (size_t)kb * 128 + bn;
        #pragma unroll
        for (int i = 0; i < 16; ++i) vals[i] = wp[(size_t)i * 128] * scl[kb + i];
    }

    f32x4 acc[8];
    #pragma unroll
    for (int s = 0; s < 8; ++s) acc[s] = (f32x4){0.f, 0.f, 0.f, 0.f};

    for (int k0 = 0; k0 < 256; k0 += 32) {
        {
            u16 hs[16], ls[16];
            #pragma unroll
            for (int i = 0; i < 16; ++i) split1(vals[i], hs[i], ls[i]);
            unsigned o0 = bn * 32 + ((ch0 ^ (bn & 3)) * 8);
            unsigned o1 = bn * 32 + (((ch0 + 1) ^ (bn & 3)) * 8);
            *(short8*)&Bh[o0] = *(short8*)&hs[0];
            *(short8*)&Bh[o1] = *(short8*)&hs[8];
            *(short8*)&Bl[o0] = *(short8*)&ls[0];
            *(short8*)&Bl[o1] = *(short8*)&ls[8];
        }
        __syncthreads();   // (1)
        short8 ah, al, bh[8], bl[8];
        {
            int row = w * 16 + l16;
            int aoff = row * 64 + ((q ^ (row & 3)) * 16);
            ah = *(const short8*)(As + aoff);
            al = *(const short8*)(As + 4096 + aoff);
            #pragma unroll
            for (int s = 0; s < 8; ++s) {
                int n = s * 16 + l16;
                int boff = n * 32 + ((q ^ (n & 3)) * 8);
                bh[s] = *(const short8*)&Bh[boff];
                bl[s] = *(const short8*)&Bl[boff];
            }
        }
        __syncthreads();   // (2)
        if (k0 + 32 < 256) {
            #pragma unroll
            for (int i = 0; i < 2; ++i) { gll16(srcs[i], As + dstoff[i]); srcs[i] += 32; }
            const float* wp = fW0 + (size_t)(k0 + 32 + kb) * 128 + bn;
            #pragma unroll
            for (int i = 0; i < 16; ++i) vals[i] = wp[(size_t)i * 128] * scl[k0 + 32 + kb + i];
        }
        #pragma unroll
        for (int s = 0; s < 8; ++s) {
            acc[s] = __builtin_amdgcn_mfma_f32_16x16x32_bf16(al, bh[s], acc[s], 0, 0, 0);
            acc[s] = __builtin_amdgcn_mfma_f32_16x16x32_bf16(ah, bl[s], acc[s], 0, 0, 0);
            acc[s] = __builtin_amdgcn_mfma_f32_16x16x32_bf16(ah, bh[s], acc[s], 0, 0, 0);
        }
    }

    // fc0 epilogue -> H3 in LDS (A-fragment layout, swizzled; pitch 128 u16)
    {
        int rowb = w * 16 + q * 4;
        #pragma unroll
        for (int s = 0; s < 8; ++s) {
            int col = s * 16 + l16;
            #pragma unroll
            for (int r = 0; r < 4; ++r) {
                int row = rowb + r;
                float v = fmaxf(acc[s][r] + biasf[col], 0.f);
                u16 h, l; split1(v, h, l);
                int c_ = col >> 3;
                int swz = ((c_ ^ (row & 7)) & 7) | (c_ & 8);
                int idx = row * 128 + swz * 8 + (col & 7);
                H3h[idx] = h;
                H3l[idx] = l;
            }
        }
    }
    __syncthreads();

    // fc1: K=128 from LDS H3; B = fW1t (pre-split, Np=64, Kp=128) from global
    f32x4 acc2[3];
    #pragma unroll
    for (int s = 0; s < 3; ++s) acc2[s] = (f32x4){0.f, 0.f, 0.f, 0.f};
    #pragma unroll
    for (int kc = 0; kc < 4; ++kc) {
        int row = w * 16 + l16;
        int c_ = kc * 4 + q;
        int swz = ((c_ ^ (row & 7)) & 7) | (c_ & 8);
        short8 ah2 = *(const short8*)&H3h[row * 128 + swz * 8];
        short8 al2 = *(const short8*)&H3l[row * 128 + swz * 8];
        #pragma unroll
        for (int s = 0; s < 3; ++s) {
            const u16* bp = fW1t + (size_t)(s * 16 + l16) * 128 + kc * 32 + q * 8;
            short8 bh2 = *(const short8*)bp;
            short8 bl2 = *(const short8*)(bp + (size_t)64 * 128);
            acc2[s] = __builtin_amdgcn_mfma_f32_16x16x32_bf16(al2, bh2, acc2[s], 0, 0, 0);
            acc2[s] = __builtin_amdgcn_mfma_f32_16x16x32_bf16(ah2, bl2, acc2[s], 0, 0, 0);
            acc2[s] = __builtin_amdgcn_mfma_f32_16x16x32_bf16(ah2, bh2, acc2[s], 0, 0, 0);
        }
    }
    {
        int growb = row0 + w * 16 + q * 4;
        #pragma unroll
        for (int s = 0; s < 3; ++s) {
            int gc = s * 16 + l16;
            if (gc >= 40) continue;
            float bia = fb1[gc];
            #pragma unroll
            for (int r = 0; r < 4; ++r) {
                int grow = growb + r;
                if (grow < NN)
                    out[(size_t)grow * 40 + gc] = fmaxf(acc2[s][r] + bia, 0.f);
            }
        }
    }
}

// ---------------- launch ----------------

extern "C" void kernel_launch(void* const* d_in, const int* in_sizes, int n_in,
                              void* d_out, int out_size, void* d_ws, size_t ws_size,
                              hipStream_t stream) {
    const float* x   = (const float*)d_in[0];
    const int*   ei  = (const int*)d_in[1];
    const float* W0  = (const float*)d_in[2];
    const float* b0  = (const float*)d_in[3];
    const float* g0  = (const float*)d_in[4];
    const float* bb0 = (const float*)d_in[5];
    const float* W1  = (const float*)d_in[6];
    const float* b1  = (const float*)d_in[7];
    const float* g1  = (const float*)d_in[8];
    const float* bb1 = (const float*)d_in[9];
    const float* fW0 = (const float*)d_in[10];
    const float* fb0 = (const float*)d_in[11];
    const float* fW1 = (const float*)d_in[12];
    const float* fb1 = (const float*)d_in[13];
    float* out = (float*)d_out;

    char* ws = (char*)d_ws;
    auto carve = [&](size_t bytes) { char* q = ws; ws += (bytes + 255) & ~(size_t)255; return q; };

    const size_t BITMAP_BYTES = (size_t)NN * ROW_WORDS * 4;   // 12,800,000
    char* region0 = carve(BITMAP_BYTES + 4096);
    unsigned int* bitmap = (unsigned int*)region0;
    float* stats = (float*)(region0 + BITMAP_BYTES);   // [0,512) conv0, [512,1024) conv1
    u16* H1 = (u16*)region0;                           // hi|lo, reuses bitmap after degree

    float* deg  = (float*)carve(MP * 4);
    u16* xs     = (u16*)carve((size_t)2 * MP * 512 * 2);
    u16* W0t    = (u16*)carve((size_t)2 * 256 * 512 * 2);
    u16* fW1t   = (u16*)carve((size_t)2 * 64 * 128 * 2);
    u16* H2     = (u16*)carve((size_t)2 * MP * 256 * 2);

    dim3 blk(256);

    // 1. zero bitmap + stats
    hipMemsetAsync(region0, 0, BITMAP_BYTES + 4096, stream);
    // 2. scatter edges
    scatter_bits<<<(NE + NN + 255) / 256, blk, 0, stream>>>(ei, bitmap);
    // 3. degree + split x/W0/fW1
    prep<<<666, blk, 0, stream>>>(bitmap, x, W0, fW1, deg, xs, W0t, fW1t);
    // 4. conv0
    conv0_gemm<<<dim3(4, 158), blk, 0, stream>>>(
        xs, xs + (size_t)MP * 512, W0t, W0t + 256 * 512,
        b0, deg, stats, H1, H1 + (size_t)MP * 256);
    // 5. conv1 (self-folds BN0 into W1)
    conv1_fold<<<dim3(4, 158), blk, 0, stream>>>(
        H1, H1 + (size_t)MP * 256, W1, stats, g0, bb0, b1, deg,
        stats + 512, H2, H2 + (size_t)MP * 256);
    // 6. fc0+fc1 fused (self-folds BN1 into fW0)
    fc_fused<<<158, blk, 0, stream>>>(
        H2, H2 + (size_t)MP * 256, fW0, stats + 512, g1, bb1, fb0, fW1t, fb1, out);
}

// Round 8
// 193.217 us; speedup vs baseline: 3.6798x; 1.2172x over previous
//
#include <hip/hip_runtime.h>

#define NN 10000
#define NE 320000
#define ROW_WORDS 320   // 320*32 = 10240 bits >= 10000
#define MP 10112        // 158*64 padded rows
#define BN_EPS 1e-5f

typedef __attribute__((ext_vector_type(8))) short short8;
typedef __attribute__((ext_vector_type(4))) float f32x4;
typedef unsigned short u16;

// ---------------- helpers ----------------
__device__ __forceinline__ void split1(float v, u16& h, u16& l) {
    unsigned int u = __float_as_uint(v);
    h = (u16)(u >> 16);
    float hf = __uint_as_float(u & 0xFFFF0000u);
    l = (u16)(__float_as_uint(v - hf) >> 16);
}

__device__ __forceinline__ void gll16(const void* g, void* l) {
    __builtin_amdgcn_global_load_lds(
        (const __attribute__((address_space(1))) unsigned int*)g,
        (__attribute__((address_space(3))) unsigned int*)l, 16, 0, 0);
}

// ---------------- scatter: dedup bitmap ----------------
__global__ void scatter_bits(const int* __restrict__ ei, unsigned int* __restrict__ bitmap) {
    int t = blockIdx.x * blockDim.x + threadIdx.x;
    if (t < NE) {
        int i = ei[t];
        int j = ei[NE + t];
        atomicOr(&bitmap[i * ROW_WORDS + (j >> 5)], 1u << (j & 31));
    } else if (t < NE + NN) {
        int i = t - NE;
        atomicOr(&bitmap[i * ROW_WORDS + (i >> 5)], 1u << (i & 31));
    }
}

// ---------------- prep device fns (proven) ----------------
__device__ void splitW_dev(const float* __restrict__ W, int K, int N, int Kp, int Np,
                           u16* __restrict__ Wt, int bx, int by, char* smem) {
    float (*tile)[65] = (float(*)[65])smem;
    int t = threadIdx.x;
    int bk = bx * 64, bn = by * 64;
    #pragma unroll
    for (int p = 0; p < 4; ++p) {
        int kk = (t >> 4) + p * 16;
        int nc = (t & 15) * 4;
        int k = bk + kk;
        float4 v = {0.f, 0.f, 0.f, 0.f};
        if (k < K && bn + nc + 3 < N)
            v = *(const float4*)&W[(size_t)k * N + bn + nc];
        tile[kk][nc] = v.x; tile[kk][nc + 1] = v.y;
        tile[kk][nc + 2] = v.z; tile[kk][nc + 3] = v.w;
    }
    __syncthreads();
    int nn = t >> 2;
    int kk0 = (t & 3) * 16;
    u16 hs[16], ls[16];
    #pragma unroll
    for (int j = 0; j < 16; ++j) split1(tile[kk0 + j][nn], hs[j], ls[j]);
    size_t ob = (size_t)(bn + nn) * Kp + bk + kk0;
    size_t lo = (size_t)Np * Kp;
    *(short8*)&Wt[ob] = *(short8*)hs;
    *(short8*)&Wt[ob + 8] = *(short8*)&hs[8];
    *(short8*)&Wt[lo + ob] = *(short8*)ls;
    *(short8*)&Wt[lo + ob + 8] = *(short8*)&ls[8];
}

__device__ void xsplit_dev(const float* __restrict__ x, u16* __restrict__ xs, int gblk) {
    int t = threadIdx.x;
    int r0 = gblk * 16 + (t >> 4);
    int l = t & 15;
    u16* xlo = xs + (size_t)MP * 512;
    #pragma unroll
    for (int j = 0; j < 8; ++j) {
        int k = (l + j * 16) * 4;
        float vals[4] = {0.f, 0.f, 0.f, 0.f};
        if (r0 < NN && k < 500) {
            float4 v = *(const float4*)&x[(size_t)r0 * 500 + k];
            vals[0] = v.x; vals[1] = v.y; vals[2] = v.z; vals[3] = v.w;
        }
        ushort4 hs, ls;
        split1(vals[0], hs.x, ls.x); split1(vals[1], hs.y, ls.y);
        split1(vals[2], hs.z, ls.z); split1(vals[3], hs.w, ls.w);
        *(ushort4*)&xs[(size_t)r0 * 512 + k] = hs;
        *(ushort4*)&xlo[(size_t)r0 * 512 + k] = ls;
    }
}

__device__ void degree_dev(const unsigned int* __restrict__ bitmap, float* __restrict__ deg,
                           int gblk) {
    int t = threadIdx.x;
    int r = gblk * 16 + (t >> 4), l = t & 15;
    int cnt = 0;
    if (r < NN)
        for (int wd = l; wd < ROW_WORDS; wd += 16)
            cnt += __popc(bitmap[(size_t)r * ROW_WORDS + wd]);
    cnt += __shfl_down(cnt, 8, 16);
    cnt += __shfl_down(cnt, 4, 16);
    cnt += __shfl_down(cnt, 2, 16);
    cnt += __shfl_down(cnt, 1, 16);
    if (l == 0 && r < NN) deg[r] = (float)cnt;
}

// ---------------- prep: degree + split x + split W0 + split fW1 ----------------
__global__ __launch_bounds__(256)
void prep(const unsigned int* __restrict__ bitmap, const float* __restrict__ x,
          const float* __restrict__ W0, const float* __restrict__ fW1,
          float* __restrict__ deg, u16* __restrict__ xs,
          u16* __restrict__ W0t, u16* __restrict__ fW1t) {
    __shared__ char smem[16704];
    int b = blockIdx.x;
    if (b < 632) {
        degree_dev(bitmap, deg, b);
        xsplit_dev(x, xs, b);
    } else if (b < 664) {
        int idx = b - 632;
        splitW_dev(W0, 500, 256, 512, 256, W0t, idx & 7, idx >> 3, smem);
    } else {
        splitW_dev(fW1, 128, 40, 128, 64, fW1t, b - 664, 0, smem);
    }
}

// ---------------- conv0 GEMM (proven) ----------------
__global__ __launch_bounds__(256, 3)
void conv0_gemm(const u16* __restrict__ Ahi, const u16* __restrict__ Alo,
                const u16* __restrict__ Bhi, const u16* __restrict__ Blo,
                const float* __restrict__ bias, const float* __restrict__ deg,
                float* __restrict__ stats, u16* __restrict__ Ohi, u16* __restrict__ Olo) {
    __shared__ char smem[32768];   // Ahi|Alo|Bhi|Blo, 8 KB each
    const int Kp = 512, M = NN, No = 256;
    const int t = threadIdx.x;
    const int lane = t & 63;
    const int w = t >> 6;
    const int q = lane >> 4;
    const int l16 = lane & 15;
    const int m7 = l16 & 7;
    const int row0 = blockIdx.y * 64;
    const int col0 = blockIdx.x * 64;

    const u16* bases[4] = {Ahi, Alo, Bhi, Blo};
    const u16* srcs[8];
    unsigned dstoff[8];
    #pragma unroll
    for (int i = 0; i < 8; ++i) {
        int gi = w + i * 4;
        int reg = i >> 1;
        int j = gi & 7;
        int rb = (reg < 2) ? row0 : col0;
        int r = j * 8 + (lane >> 3);
        int c = (lane & 7) ^ (r & 7);
        srcs[i] = bases[reg] + (size_t)(rb + r) * Kp + c * 8;
        dstoff[i] = reg * 8192 + j * 1024;
    }

    f32x4 acc[4];
    #pragma unroll
    for (int s = 0; s < 4; ++s) acc[s] = (f32x4){0.f, 0.f, 0.f, 0.f};

    #pragma unroll
    for (int i = 0; i < 8; ++i) { gll16(srcs[i], smem + dstoff[i]); srcs[i] += 64; }

    for (int k0 = 0; k0 < Kp; k0 += 64) {
        __syncthreads();
        short8 ah[2], al[2], bh[2][4], bl[2][4];
        #pragma unroll
        for (int kc = 0; kc < 2; ++kc) {
            int aoff = (w * 16 + l16) * 128 + (((kc * 4 + q) ^ m7) * 16);
            ah[kc] = *(const short8*)(smem + aoff);
            al[kc] = *(const short8*)(smem + 8192 + aoff);
            #pragma unroll
            for (int s = 0; s < 4; ++s) {
                int boff = (s * 16 + l16) * 128 + (((kc * 4 + q) ^ m7) * 16);
                bh[kc][s] = *(const short8*)(smem + 16384 + boff);
                bl[kc][s] = *(const short8*)(smem + 24576 + boff);
            }
        }
        __syncthreads();
        if (k0 + 64 < Kp) {
            #pragma unroll
            for (int i = 0; i < 8; ++i) { gll16(srcs[i], smem + dstoff[i]); srcs[i] += 64; }
        }
        #pragma unroll
        for (int kc = 0; kc < 2; ++kc)
            #pragma unroll
            for (int s = 0; s < 4; ++s) {
                acc[s] = __builtin_amdgcn_mfma_f32_16x16x32_bf16(al[kc], bh[kc][s], acc[s], 0, 0, 0);
                acc[s] = __builtin_amdgcn_mfma_f32_16x16x32_bf16(ah[kc], bl[kc][s], acc[s], 0, 0, 0);
                acc[s] = __builtin_amdgcn_mfma_f32_16x16x32_bf16(ah[kc], bh[kc][s], acc[s], 0, 0, 0);
            }
    }

    int growb = row0 + w * 16 + q * 4;
    float dgv[4];
    #pragma unroll
    for (int r = 0; r < 4; ++r) dgv[r] = (growb + r < M) ? deg[growb + r] : 0.f;
    #pragma unroll
    for (int s = 0; s < 4; ++s) {
        int gc = col0 + s * 16 + l16;
        float bia = bias[gc];
        float s_sum = 0.f, ss_sum = 0.f;
        #pragma unroll
        for (int r = 0; r < 4; ++r) {
            int grow = growb + r;
            bool real = grow < M;
            float v = fmaxf(fmaf(dgv[r], acc[s][r], bia), 0.f);
            if (!real) v = 0.f;
            s_sum += v; ss_sum += v * v;
            float vo = v * dgv[r];
            u16 h, l; split1(vo, h, l);
            Ohi[(size_t)grow * No + gc] = h;
            Olo[(size_t)grow * No + gc] = l;
        }
        s_sum  += __shfl_xor(s_sum, 16);  s_sum  += __shfl_xor(s_sum, 32);
        ss_sum += __shfl_xor(ss_sum, 16); ss_sum += __shfl_xor(ss_sum, 32);
        if (lane < 16) {
            atomicAdd(&stats[gc], s_sum);
            atomicAdd(&stats[256 + gc], ss_sum);
        }
    }
}

// ---------------- conv1 with in-kernel BN0 fold of W1 (proven, + unroll fix) ----------------
__global__ __launch_bounds__(256, 2)
void conv1_fold(const u16* __restrict__ Ahi, const u16* __restrict__ Alo,
                const float* __restrict__ W1, const float* __restrict__ stats0,
                const float* __restrict__ g0, const float* __restrict__ bb0,
                const float* __restrict__ b1, const float* __restrict__ deg,
                float* __restrict__ stats1, u16* __restrict__ Ohi, u16* __restrict__ Olo) {
    __shared__ char smem[32768];
    __shared__ float scl[256], sh[256], cred[256], cvec[64];
    const int Kp = 256, M = NN, No = 256;
    const int t = threadIdx.x;
    const int lane = t & 63;
    const int w = t >> 6;
    const int q = lane >> 4;
    const int l16 = lane & 15;
    const int m7 = l16 & 7;
    const int row0 = blockIdx.y * 64;
    const int col0 = blockIdx.x * 64;

    const u16* srcs[4];
    unsigned dstoff[4];
    #pragma unroll
    for (int i = 0; i < 4; ++i) {
        int gi = w + i * 4;
        int plane = gi >> 3, j = gi & 7;
        int r = j * 8 + (lane >> 3);
        int c = (lane & 7) ^ (r & 7);
        srcs[i] = (plane ? Alo : Ahi) + (size_t)(row0 + r) * Kp + c * 8;
        dstoff[i] = plane * 8192 + j * 1024;
    }
    #pragma unroll
    for (int i = 0; i < 4; ++i) { gll16(srcs[i], smem + dstoff[i]); srcs[i] += 64; }

    {
        float mean = stats0[t] * (1.f / NN);
        float var = stats0[256 + t] * (1.f / NN) - mean * mean;
        float s = g0[t] * rsqrtf(var + BN_EPS);
        scl[t] = s;
        sh[t] = bb0[t] - mean * s;
    }
    __syncthreads();
    {
        float s = 0.f;
        int n = col0 + (t & 63);
        #pragma unroll 8
        for (int k = (t >> 6); k < 256; k += 4)
            s += sh[k] * W1[(size_t)k * 256 + n];
        cred[t] = s;
        __syncthreads();
        if (t < 64) cvec[t] = cred[t] + cred[t + 64] + cred[t + 128] + cred[t + 192];
    }
    const int bn = t & 63;
    const int kb = (t >> 6) * 16;
    const int ch0 = (t >> 6) * 2;
    float vals[16];
    {
        const float* wp = W1 + (size_t)kb * 256 + col0 + bn;
        #pragma unroll
        for (int i = 0; i < 16; ++i) vals[i] = wp[(size_t)i * 256] * scl[kb + i];
    }

    f32x4 acc[4];
    #pragma unroll
    for (int s = 0; s < 4; ++s) acc[s] = (f32x4){0.f, 0.f, 0.f, 0.f};

    for (int k0 = 0; k0 < Kp; k0 += 64) {
        {
            u16 hs[16], ls[16];
            #pragma unroll
            for (int i = 0; i < 16; ++i) split1(vals[i], hs[i], ls[i]);
            unsigned o0 = bn * 128 + ((ch0 ^ (bn & 7)) * 16);
            unsigned o1 = bn * 128 + (((ch0 + 1) ^ (bn & 7)) * 16);
            *(short8*)(smem + 16384 + o0) = *(short8*)&hs[0];
            *(short8*)(smem + 16384 + o1) = *(short8*)&hs[8];
            *(short8*)(smem + 24576 + o0) = *(short8*)&ls[0];
            *(short8*)(smem + 24576 + o1) = *(short8*)&ls[8];
        }
        __syncthreads();   // (1)
        short8 ah[2], al[2], bh[2][4], bl[2][4];
        #pragma unroll
        for (int kc = 0; kc < 2; ++kc) {
            int aoff = (w * 16 + l16) * 128 + (((kc * 4 + q) ^ m7) * 16);
            ah[kc] = *(const short8*)(smem + aoff);
            al[kc] = *(const short8*)(smem + 8192 + aoff);
            #pragma unroll
            for (int s = 0; s < 4; ++s) {
                int boff = (s * 16 + l16) * 128 + (((kc * 4 + q) ^ m7) * 16);
                bh[kc][s] = *(const short8*)(smem + 16384 + boff);
                bl[kc][s] = *(const short8*)(smem + 24576 + boff);
            }
        }
        __syncthreads();   // (2)
        if (k0 + 64 < Kp) {
            #pragma unroll
            for (int i = 0; i < 4; ++i) { gll16(srcs[i], smem + dstoff[i]); srcs[i] += 64; }
            const float* wp = W1 + (size_t)(k0 + 64 + kb) * 256 + col0 + bn;
            #pragma unroll
            for (int i = 0; i < 16; ++i) vals[i] = wp[(size_t)i * 256] * scl[k0 + 64 + kb + i];
        }
        #pragma unroll
        for (int kc = 0; kc < 2; ++kc)
            #pragma unroll
            for (int s = 0; s < 4; ++s) {
                acc[s] = __builtin_amdgcn_mfma_f32_16x16x32_bf16(al[kc], bh[kc][s], acc[s], 0, 0, 0);
                acc[s] = __builtin_amdgcn_mfma_f32_16x16x32_bf16(ah[kc], bl[kc][s], acc[s], 0, 0, 0);
                acc[s] = __builtin_amdgcn_mfma_f32_16x16x32_bf16(ah[kc], bh[kc][s], acc[s], 0, 0, 0);
            }
    }

    int growb = row0 + w * 16 + q * 4;
    float dgv[4];
    #pragma unroll
    for (int r = 0; r < 4; ++r) dgv[r] = (growb + r < M) ? deg[growb + r] : 0.f;
    #pragma unroll
    for (int s = 0; s < 4; ++s) {
        int gc = col0 + s * 16 + l16;
        float bia = b1[gc];
        float cv = cvec[s * 16 + l16];
        float s_sum = 0.f, ss_sum = 0.f;
        #pragma unroll
        for (int r = 0; r < 4; ++r) {
            int grow = growb + r;
            bool real = grow < M;
            float v = fmaxf(fmaf(dgv[r], cv, acc[s][r] + bia), 0.f);
            if (!real) v = 0.f;
            s_sum += v; ss_sum += v * v;
            u16 h, l; split1(v, h, l);
            Ohi[(size_t)grow * No + gc] = h;
            Olo[(size_t)grow * No + gc] = l;
        }
        s_sum  += __shfl_xor(s_sum, 16);  s_sum  += __shfl_xor(s_sum, 32);
        ss_sum += __shfl_xor(ss_sum, 16); ss_sum += __shfl_xor(ss_sum, 32);
        if (lane < 16) {
            atomicAdd(&stats1[gc], s_sum);
            atomicAdd(&stats1[256 + gc], ss_sum);
        }
    }
}

// ---------------- fc0 with in-kernel BN1 fold of fW0 (conv1_fold clone, no deg/stats) ----
// H3 = relu(BN1(H2)@fW0 + fb0), split output. Grid (2, 158).
__global__ __launch_bounds__(256, 2)
void fc0_fold(const u16* __restrict__ Ahi, const u16* __restrict__ Alo,
              const float* __restrict__ fW0, const float* __restrict__ stats1,
              const float* __restrict__ g1, const float* __restrict__ bb1,
              const float* __restrict__ fb0,
              u16* __restrict__ Ohi, u16* __restrict__ Olo) {
    __shared__ char smem[32768];
    __shared__ float scl[256], sh[256], cred[256], biasf[64];
    const int Kp = 256, M = NN, No = 128;
    const int t = threadIdx.x;
    const int lane = t & 63;
    const int w = t >> 6;
    const int q = lane >> 4;
    const int l16 = lane & 15;
    const int m7 = l16 & 7;
    const int row0 = blockIdx.y * 64;
    const int col0 = blockIdx.x * 64;

    const u16* srcs[4];
    unsigned dstoff[4];
    #pragma unroll
    for (int i = 0; i < 4; ++i) {
        int gi = w + i * 4;
        int plane = gi >> 3, j = gi & 7;
        int r = j * 8 + (lane >> 3);
        int c = (lane & 7) ^ (r & 7);
        srcs[i] = (plane ? Alo : Ahi) + (size_t)(row0 + r) * Kp + c * 8;
        dstoff[i] = plane * 8192 + j * 1024;
    }
    #pragma unroll
    for (int i = 0; i < 4; ++i) { gll16(srcs[i], smem + dstoff[i]); srcs[i] += 64; }

    {
        float mean = stats1[t] * (1.f / NN);
        float var = stats1[256 + t] * (1.f / NN) - mean * mean;
        float s = g1[t] * rsqrtf(var + BN_EPS);
        scl[t] = s;
        sh[t] = bb1[t] - mean * s;
    }
    __syncthreads();
    {
        float s = 0.f;
        int n = col0 + (t & 63);
        #pragma unroll 8
        for (int k = (t >> 6); k < 256; k += 4)
            s += sh[k] * fW0[(size_t)k * 128 + n];
        cred[t] = s;
        __syncthreads();
        if (t < 64)
            biasf[t] = fb0[col0 + t] + cred[t] + cred[t + 64] + cred[t + 128] + cred[t + 192];
    }
    const int bn = t & 63;
    const int kb = (t >> 6) * 16;
    const int ch0 = (t >> 6) * 2;
    float vals[16];
    {
        const float* wp = fW0 + (size_t)kb * 128 + col0 + bn;
        #pragma unroll
        for (int i = 0; i < 16; ++i) vals[i] = wp[(size_t)i * 128] * scl[kb + i];
    }

    f32x4 acc[4];
    #pragma unroll
    for (int s = 0; s < 4; ++s) acc[s] = (f32x4){0.f, 0.f, 0.f, 0.f};

    for (int k0 = 0; k0 < Kp; k0 += 64) {
        {
            u16 hs[16], ls[16];
            #pragma unroll
            for (int i = 0; i < 16; ++i) split1(vals[i], hs[i], ls[i]);
            unsigned o0 = bn * 128 + ((ch0 ^ (bn & 7)) * 16);
            unsigned o1 = bn * 128 + (((ch0 + 1) ^ (bn & 7)) * 16);
            *(short8*)(smem + 16384 + o0) = *(short8*)&hs[0];
            *(short8*)(smem + 16384 + o1) = *(short8*)&hs[8];
            *(short8*)(smem + 24576 + o0) = *(short8*)&ls[0];
            *(short8*)(smem + 24576 + o1) = *(short8*)&ls[8];
        }
        __syncthreads();   // (1)
        short8 ah[2], al[2], bh[2][4], bl[2][4];
        #pragma unroll
        for (int kc = 0; kc < 2; ++kc) {
            int aoff = (w * 16 + l16) * 128 + (((kc * 4 + q) ^ m7) * 16);
            ah[kc] = *(const short8*)(smem + aoff);
            al[kc] = *(const short8*)(smem + 8192 + aoff);
            #pragma unroll
            for (int s = 0; s < 4; ++s) {
                int boff = (s * 16 + l16) * 128 + (((kc * 4 + q) ^ m7) * 16);
                bh[kc][s] = *(const short8*)(smem + 16384 + boff);
                bl[kc][s] = *(const short8*)(smem + 24576 + boff);
            }
        }
        __syncthreads();   // (2)
        if (k0 + 64 < Kp) {
            #pragma unroll
            for (int i = 0; i < 4; ++i) { gll16(srcs[i], smem + dstoff[i]); srcs[i] += 64; }
            const float* wp = fW0 + (size_t)(k0 + 64 + kb) * 128 + col0 + bn;
            #pragma unroll
            for (int i = 0; i < 16; ++i) vals[i] = wp[(size_t)i * 128] * scl[k0 + 64 + kb + i];
        }
        #pragma unroll
        for (int kc = 0; kc < 2; ++kc)
            #pragma unroll
            for (int s = 0; s < 4; ++s) {
                acc[s] = __builtin_amdgcn_mfma_f32_16x16x32_bf16(al[kc], bh[kc][s], acc[s], 0, 0, 0);
                acc[s] = __builtin_amdgcn_mfma_f32_16x16x32_bf16(ah[kc], bl[kc][s], acc[s], 0, 0, 0);
                acc[s] = __builtin_amdgcn_mfma_f32_16x16x32_bf16(ah[kc], bh[kc][s], acc[s], 0, 0, 0);
            }
    }

    int growb = row0 + w * 16 + q * 4;
    #pragma unroll
    for (int s = 0; s < 4; ++s) {
        int gc = col0 + s * 16 + l16;
        float bia = biasf[s * 16 + l16];
        #pragma unroll
        for (int r = 0; r < 4; ++r) {
            int grow = growb + r;
            float v = fmaxf(acc[s][r] + bia, 0.f);
            if (grow >= M) v = 0.f;
            u16 h, l; split1(v, h, l);
            Ohi[(size_t)grow * No + gc] = h;
            Olo[(size_t)grow * No + gc] = l;
        }
    }
}

// ---------------- fc1: proven generic gemm, Kp=128, N=40, fp32 out ----------------
__global__ __launch_bounds__(256, 3)
void fc1_gemm(const u16* __restrict__ Ahi, const u16* __restrict__ Alo,
              const u16* __restrict__ Bhi, const u16* __restrict__ Blo,
              const float* __restrict__ bias, float* __restrict__ out) {
    __shared__ char smem[32768];
    const int Kp = 128, M = NN, N = 40, No = 40;
    const int t = threadIdx.x;
    const int lane = t & 63;
    const int w = t >> 6;
    const int q = lane >> 4;
    const int l16 = lane & 15;
    const int m7 = l16 & 7;
    const int row0 = blockIdx.y * 64;
    const int col0 = 0;

    const u16* bases[4] = {Ahi, Alo, Bhi, Blo};
    const u16* srcs[8];
    unsigned dstoff[8];
    #pragma unroll
    for (int i = 0; i < 8; ++i) {
        int gi = w + i * 4;
        int reg = i >> 1;
        int j = gi & 7;
        int rb = (reg < 2) ? row0 : col0;
        int r = j * 8 + (lane >> 3);
        int c = (lane & 7) ^ (r & 7);
        srcs[i] = bases[reg] + (size_t)(rb + r) * Kp + c * 8;
        dstoff[i] = reg * 8192 + j * 1024;
    }

    f32x4 acc[4];
    #pragma unroll
    for (int s = 0; s < 4; ++s) acc[s] = (f32x4){0.f, 0.f, 0.f, 0.f};

    #pragma unroll
    for (int i = 0; i < 8; ++i) { gll16(srcs[i], smem + dstoff[i]); srcs[i] += 64; }

    for (int k0 = 0; k0 < Kp; k0 += 64) {
        __syncthreads();
        short8 ah[2], al[2], bh[2][4], bl[2][4];
        #pragma unroll
        for (int kc = 0; kc < 2; ++kc) {
            int aoff = (w * 16 + l16) * 128 + (((kc * 4 + q) ^ m7) * 16);
            ah[kc] = *(const short8*)(smem + aoff);
            al[kc] = *(const short8*)(smem + 8192 + aoff);
            #pragma unroll
            for (int s = 0; s < 4; ++s) {
                int boff = (s * 16 + l16) * 128 + (((kc * 4 + q) ^ m7) * 16);
                bh[kc][s] = *(const short8*)(smem + 16384 + boff);
                bl[kc][s] = *(const short8*)(smem + 24576 + boff);
            }
        }
        __syncthreads();
        if (k0 + 64 < Kp) {
            #pragma unroll
            for (int i = 0; i < 8; ++i) { gll16(srcs[i], smem + dstoff[i]); srcs[i] += 64; }
        }
        #pragma unroll
        for (int kc = 0; kc < 2; ++kc)
            #pragma unroll
            for (int s = 0; s < 4; ++s) {
                acc[s] = __builtin_amdgcn_mfma_f32_16x16x32_bf16(al[kc], bh[kc][s], acc[s], 0, 0, 0);
                acc[s] = __builtin_amdgcn_mfma_f32_16x16x32_bf16(ah[kc], bl[kc][s], acc[s], 0, 0, 0);
                acc[s] = __builtin_amdgcn_mfma_f32_16x16x32_bf16(ah[kc], bh[kc][s], acc[s], 0, 0, 0);
            }
    }

    int growb = row0 + w * 16 + q * 4;
    #pragma unroll
    for (int s = 0; s < 4; ++s) {
        int gc = col0 + s * 16 + l16;
        if (gc >= N) continue;
        float bia = bias[gc];
        #pragma unroll
        for (int r = 0; r < 4; ++r) {
            int grow = growb + r;
            if (grow < M)
                out[(size_t)grow * No + gc] = fmaxf(acc[s][r] + bia, 0.f);
        }
    }
}

// ---------------- launch ----------------

extern "C" void kernel_launch(void* const* d_in, const int* in_sizes, int n_in,
                              void* d_out, int out_size, void* d_ws, size_t ws_size,
                              hipStream_t stream) {
    const float* x   = (const float*)d_in[0];
    const int*   ei  = (const int*)d_in[1];
    const float* W0  = (const float*)d_in[2];
    const float* b0  = (const float*)d_in[3];
    const float* g0  = (const float*)d_in[4];
    const float* bb0 = (const float*)d_in[5];
    const float* W1  = (const float*)d_in[6];
    const float* b1  = (const float*)d_in[7];
    const float* g1  = (const float*)d_in[8];
    const float* bb1 = (const float*)d_in[9];
    const float* fW0 = (const float*)d_in[10];
    const float* fb0 = (const float*)d_in[11];
    const float* fW1 = (const float*)d_in[12];
    const float* fb1 = (const float*)d_in[13];
    float* out = (float*)d_out;

    char* ws = (char*)d_ws;
    auto carve = [&](size_t bytes) { char* q = ws; ws += (bytes + 255) & ~(size_t)255; return q; };

    const size_t BITMAP_BYTES = (size_t)NN * ROW_WORDS * 4;   // 12,800,000
    char* region0 = carve(BITMAP_BYTES + 4096);
    unsigned int* bitmap = (unsigned int*)region0;
    float* stats = (float*)(region0 + BITMAP_BYTES);   // [0,512) conv0, [512,1024) conv1
    u16* H1 = (u16*)region0;                           // hi|lo, reuses bitmap after degree

    float* deg  = (float*)carve(MP * 4);
    u16* xs     = (u16*)carve((size_t)2 * MP * 512 * 2);
    u16* W0t    = (u16*)carve((size_t)2 * 256 * 512 * 2);
    u16* fW1t   = (u16*)carve((size_t)2 * 64 * 128 * 2);
    u16* H2     = (u16*)carve((size_t)2 * MP * 256 * 2);
    u16* H3     = (u16*)carve((size_t)2 * MP * 128 * 2);

    dim3 blk(256);

    // 1. zero bitmap + stats
    hipMemsetAsync(region0, 0, BITMAP_BYTES + 4096, stream);
    // 2. scatter edges
    scatter_bits<<<(NE + NN + 255) / 256, blk, 0, stream>>>(ei, bitmap);
    // 3. degree + split x/W0/fW1
    prep<<<666, blk, 0, stream>>>(bitmap, x, W0, fW1, deg, xs, W0t, fW1t);
    // 4. conv0
    conv0_gemm<<<dim3(4, 158), blk, 0, stream>>>(
        xs, xs + (size_t)MP * 512, W0t, W0t + 256 * 512,
        b0, deg, stats, H1, H1 + (size_t)MP * 256);
    // 5. conv1 (self-folds BN0 into W1)
    conv1_fold<<<dim3(4, 158), blk, 0, stream>>>(
        H1, H1 + (size_t)MP * 256, W1, stats, g0, bb0, b1, deg,
        stats + 512, H2, H2 + (size_t)MP * 256);
    // 6. fc0 (self-folds BN1 into fW0)
    fc0_fold<<<dim3(2, 158), blk, 0, stream>>>(
        H2, H2 + (size_t)MP * 256, fW0, stats + 512, g1, bb1, fb0,
        H3, H3 + (size_t)MP * 128);
    // 7. fc1
    fc1_gemm<<<dim3(1, 158), blk, 0, stream>>>(
        H3, H3 + (size_t)MP * 128, fW1t, fW1t + 64 * 128, fb1, out);
}